// Round 1
// baseline (3146.034 us; speedup 1.0000x reference)
//
#include <hip/hip_runtime.h>
#include <hip/hip_bf16.h>

// Problem constants (validated at runtime from in_sizes):
//   x[N,128] f32, edge_index[2,E] int, edge_label[E,4] f32,
//   weight[512,256] f32, trans_weight[4,128] f32, bias[256] f32
//   out[N,256] f32
//
// Algebra: scatter_mean(edge_label @ tw, idx) == (scatter_sum(edge_label, idx) @ tw)/deg
// and (lab/deg) @ tw @ W1 == (lab/deg) @ P1 with P1 = tw@W1 (4x256).
// So per-edge we only accumulate: x[col]->out_sum[row], x[row]->inn_sum[col],
// label->lab_row[row], label->lab_col[col], and degrees.

__global__ __launch_bounds__(256) void scatter_kernel(
    const float* __restrict__ x, const int* __restrict__ eidx,
    const float* __restrict__ elabel,
    float* __restrict__ out_sum, float* __restrict__ inn_sum,
    float* __restrict__ lab_row, float* __restrict__ lab_col,
    float* __restrict__ deg_row, float* __restrict__ deg_col, int n_edges)
{
    const int lane = threadIdx.x;                 // 0..63 : one wave handles one edge
    const int e = blockIdx.x * 4 + threadIdx.y;   // 4 edges per 256-thread block
    if (e >= n_edges) return;
    const int row = eidx[e];
    const int col = eidx[n_edges + e];
    const float2* __restrict__ x2 = (const float2*)x;
    const float2 xc = x2[(size_t)col * 64 + lane];   // x[col][2*lane .. 2*lane+1]
    const float2 xr = x2[(size_t)row * 64 + lane];
    float* po = out_sum + (size_t)row * 128 + 2 * lane;
    float* pi = inn_sum + (size_t)col * 128 + 2 * lane;
    unsafeAtomicAdd(po, xc.x);
    unsafeAtomicAdd(po + 1, xc.y);
    unsafeAtomicAdd(pi, xr.x);
    unsafeAtomicAdd(pi + 1, xr.y);
    if (lane < 4) {
        const float lv = elabel[(size_t)e * 4 + lane];
        unsafeAtomicAdd(&lab_row[(size_t)row * 4 + lane], lv);
        unsafeAtomicAdd(&lab_col[(size_t)col * 4 + lane], lv);
    } else if (lane == 8) {
        unsafeAtomicAdd(&deg_row[row], 1.0f);
    } else if (lane == 9) {
        unsafeAtomicAdd(&deg_col[col], 1.0f);
    }
}

__global__ void inv_kernel(const float* __restrict__ deg_r, const float* __restrict__ deg_c,
                           float* __restrict__ inv_r, float* __restrict__ inv_c, int n)
{
    const int i = blockIdx.x * 256 + threadIdx.x;
    if (i < n) {
        inv_r[i] = 1.0f / fmaxf(deg_r[i], 1.0f);
        inv_c[i] = 1.0f / fmaxf(deg_c[i], 1.0f);
    }
}

// P1 = tw @ weight[128:256]  (4x256), P3 = tw @ weight[384:512]  (4x256)
__global__ void precompute_p(const float* __restrict__ tw, const float* __restrict__ weight,
                             float* __restrict__ P1, float* __restrict__ P3)
{
    const int o = threadIdx.x;   // 256 threads, one output column each
    #pragma unroll
    for (int l = 0; l < 4; ++l) {
        float s1 = 0.f, s3 = 0.f;
        for (int c = 0; c < 128; ++c) {
            const float t = tw[l * 128 + c];
            s1 = fmaf(t, weight[(size_t)(128 + c) * 256 + o], s1);
            s3 = fmaf(t, weight[(size_t)(384 + c) * 256 + o], s3);
        }
        P1[l * 256 + o] = s1;
        P3[l * 256 + o] = s3;
    }
}

// out[64 nodes x 256 cols] per block. K main loop = 256 (out_mean 128 + inn_mean 128),
// plus rank-8 epilogue for opinion terms via P1/P3.
__global__ __launch_bounds__(256) void gemm_kernel(
    const float* __restrict__ out_sum, const float* __restrict__ inn_sum,
    const float* __restrict__ lab_row, const float* __restrict__ lab_col,
    const float* __restrict__ inv_dr, const float* __restrict__ inv_dc,
    const float* __restrict__ weight, const float* __restrict__ P1,
    const float* __restrict__ P3, const float* __restrict__ bias,
    float* __restrict__ out, int n_nodes)
{
    __shared__ float hs[64][33];    // h tile [node][kk], padded
    __shared__ float ws[32][256];   // weight tile [kk][out col]
    __shared__ float ps[8][256];    // P1 rows 0..3, P3 rows 0..3
    __shared__ float labs[64][8];   // per-node lab_row*inv_dr (4) ++ lab_col*inv_dc (4)

    const int t = threadIdx.x;
    const int tx = t & 31;          // output-col group
    const int ty = t >> 5;          // node group
    const int node0 = blockIdx.x * 64;

    float acc[8][8];
    #pragma unroll
    for (int i = 0; i < 8; ++i)
        #pragma unroll
        for (int j = 0; j < 8; ++j) acc[i][j] = 0.f;

    for (int i = t; i < 2048; i += 256) {
        const int l = i >> 8, c = i & 255;
        ps[l][c] = (l < 4) ? P1[l * 256 + c] : P3[(l - 4) * 256 + c];
    }
    for (int i = t; i < 512; i += 256) {
        const int node = i >> 3, l = i & 7;
        const int gn = node0 + node;
        float v = 0.f;
        if (gn < n_nodes)
            v = (l < 4) ? lab_row[(size_t)gn * 4 + l] * inv_dr[gn]
                        : lab_col[(size_t)gn * 4 + (l - 4)] * inv_dc[gn];
        labs[node][l] = v;
    }

    for (int kt = 0; kt < 8; ++kt) {
        const float* __restrict__ src = (kt < 4) ? out_sum : inn_sum;
        const float* __restrict__ inv = (kt < 4) ? inv_dr : inv_dc;
        const int cbase = (kt & 3) * 32;
        const int wrow0 = (kt < 4) ? kt * 32 : 256 + (kt - 4) * 32;

        __syncthreads();   // protect hs/ws from previous iteration's readers

        // stage h tile: thread -> node t>>2, kk = (t&3)*8 + 0..7 (8 consecutive floats)
        {
            const int node = t >> 2;
            const int gn = node0 + node;
            const int kk0 = (t & 3) * 8;
            float invv = 0.f;
            float4 a0 = make_float4(0.f, 0.f, 0.f, 0.f), a1 = a0;
            if (gn < n_nodes) {
                invv = inv[gn];
                const float4* s4 = (const float4*)(src + (size_t)gn * 128 + cbase + kk0);
                a0 = s4[0]; a1 = s4[1];
            }
            hs[node][kk0 + 0] = a0.x * invv;
            hs[node][kk0 + 1] = a0.y * invv;
            hs[node][kk0 + 2] = a0.z * invv;
            hs[node][kk0 + 3] = a0.w * invv;
            hs[node][kk0 + 4] = a1.x * invv;
            hs[node][kk0 + 5] = a1.y * invv;
            hs[node][kk0 + 6] = a1.z * invv;
            hs[node][kk0 + 7] = a1.w * invv;
        }
        // stage weight tile (coalesced: lane-consecutive columns)
        for (int kk = 0; kk < 32; ++kk)
            ws[kk][t] = weight[(size_t)(wrow0 + kk) * 256 + t];

        __syncthreads();

        for (int kk = 0; kk < 32; ++kk) {
            float a[8], b[8];
            #pragma unroll
            for (int j = 0; j < 8; ++j) b[j] = ws[kk][tx + 32 * j];   // conflict-free
            #pragma unroll
            for (int i = 0; i < 8; ++i) a[i] = hs[ty * 8 + i][kk];    // wave broadcast
            #pragma unroll
            for (int i = 0; i < 8; ++i)
                #pragma unroll
                for (int j = 0; j < 8; ++j)
                    acc[i][j] = fmaf(a[i], b[j], acc[i][j]);
        }
    }

    #pragma unroll
    for (int i = 0; i < 8; ++i) {
        const int node = ty * 8 + i;
        const int gn = node0 + node;
        if (gn >= n_nodes) continue;
        #pragma unroll
        for (int j = 0; j < 8; ++j) {
            const int oc = tx + 32 * j;
            float v = acc[i][j] + bias[oc];
            #pragma unroll
            for (int l = 0; l < 8; ++l) v = fmaf(labs[node][l], ps[l][oc], v);
            out[(size_t)gn * 256 + oc] = v;
        }
    }
}

extern "C" void kernel_launch(void* const* d_in, const int* in_sizes, int n_in,
                              void* d_out, int out_size, void* d_ws, size_t ws_size,
                              hipStream_t stream) {
    const float* x      = (const float*)d_in[0];
    const int*   eidx   = (const int*)d_in[1];
    const float* elabel = (const float*)d_in[2];
    const float* weight = (const float*)d_in[3];
    const float* tw     = (const float*)d_in[4];
    const float* bias   = (const float*)d_in[5];

    const int n_nodes = in_sizes[0] / 128;
    const int n_edges = in_sizes[2] / 4;

    float* wf = (float*)d_ws;
    size_t o = 0;
    float* out_sum = wf + o; o += (size_t)n_nodes * 128;
    float* inn_sum = wf + o; o += (size_t)n_nodes * 128;
    float* lab_row = wf + o; o += (size_t)n_nodes * 4;
    float* lab_col = wf + o; o += (size_t)n_nodes * 4;
    float* deg_row = wf + o; o += n_nodes;
    float* deg_col = wf + o; o += n_nodes;
    const size_t zero_floats = o;                 // everything above must start at 0
    float* inv_dr  = wf + o; o += n_nodes;
    float* inv_dc  = wf + o; o += n_nodes;
    float* P1      = wf + o; o += 1024;
    float* P3      = wf + o; o += 1024;

    hipMemsetAsync(d_ws, 0, zero_floats * sizeof(float), stream);

    hipLaunchKernelGGL(precompute_p, dim3(1), dim3(256), 0, stream, tw, weight, P1, P3);

    dim3 sblock(64, 4);
    hipLaunchKernelGGL(scatter_kernel, dim3((n_edges + 3) / 4), sblock, 0, stream,
                       x, eidx, elabel, out_sum, inn_sum, lab_row, lab_col,
                       deg_row, deg_col, n_edges);

    hipLaunchKernelGGL(inv_kernel, dim3((n_nodes + 255) / 256), dim3(256), 0, stream,
                       deg_row, deg_col, inv_dr, inv_dc, n_nodes);

    hipLaunchKernelGGL(gemm_kernel, dim3((n_nodes + 63) / 64), dim3(256), 0, stream,
                       out_sum, inn_sum, lab_row, lab_col, inv_dr, inv_dc,
                       weight, P1, P3, bias, (float*)d_out, n_nodes);
}

// Round 2
// 1004.636 us; speedup vs baseline: 3.1315x; 3.1315x over previous
//
#include <hip/hip_runtime.h>
#include <hip/hip_bf16.h>

// x[N,128] f32, edge_index[2,E] int, edge_label[E,4] f32,
// weight[512,256] f32, trans_weight[4,128] f32, bias[256] f32 -> out[N,256] f32
//
// Algebra: scatter_mean(edge_label @ tw, idx) == (scatter_sum(edge_label, idx)/deg) @ tw
// and (lab/deg) @ tw @ W1 == (lab/deg) @ P1 with P1 = tw@W1 (4x256).
//
// Strategy: CSR counting-sort of edges by row and by col (int atomics only),
// then one wave per node accumulates x[other] rows + labels in registers and
// writes the MEAN once. No f32 atomics anywhere. Sorted edge lists are staged
// in d_out (consumed before the final GEMM overwrites it).

__global__ void hist_kernel(const int* __restrict__ eidx,
                            int* __restrict__ cnt_r, int* __restrict__ cnt_c, int E)
{
    const int i = blockIdx.x * 256 + threadIdx.x;
    if (i >= 2 * E) return;
    const int v = eidx[i];
    atomicAdd(i < E ? &cnt_r[v] : &cnt_c[v], 1);
}

__global__ __launch_bounds__(1024) void scan1(const int* __restrict__ cnt,
                                              int* __restrict__ bsum, int n)
{
    __shared__ int red[1024];
    const int t = threadIdx.x;
    const int i = blockIdx.x * 1024 + t;
    red[t] = (i < n) ? cnt[i] : 0;
    __syncthreads();
    for (int s = 512; s > 0; s >>= 1) {
        if (t < s) red[t] += red[t + s];
        __syncthreads();
    }
    if (t == 0) bsum[blockIdx.x] = red[0];
}

__global__ void scan2(int* __restrict__ bsum, int nb, int* __restrict__ rowptr,
                      int n, int total)
{
    if (threadIdx.x == 0) {
        int off = 0;
        for (int b = 0; b < nb; ++b) { const int t = bsum[b]; bsum[b] = off; off += t; }
        rowptr[n] = total;
    }
}

// writes exclusive prefix to rowptr[i] and also into cnt[i] (reused as fill cursor)
__global__ __launch_bounds__(1024) void scan3(int* __restrict__ cnt,
                                              const int* __restrict__ bsum,
                                              int* __restrict__ rowptr, int n)
{
    __shared__ int sh[1024];
    const int t = threadIdx.x;
    const int i = blockIdx.x * 1024 + t;
    const int v = (i < n) ? cnt[i] : 0;
    sh[t] = v;
    __syncthreads();
    for (int s = 1; s < 1024; s <<= 1) {
        int tmp = 0;
        if (t >= s) tmp = sh[t - s];
        __syncthreads();
        sh[t] += tmp;
        __syncthreads();
    }
    if (i < n) {
        const int excl = sh[t] - v + bsum[blockIdx.x];
        rowptr[i] = excl;
        cnt[i] = excl;
    }
}

__global__ void fill_kernel(const int* __restrict__ eidx,
                            int* __restrict__ cur_r, int* __restrict__ cur_c,
                            uint2* __restrict__ srt_r, uint2* __restrict__ srt_c, int E)
{
    const int e = blockIdx.x * 256 + threadIdx.x;
    if (e >= E) return;
    const int row = eidx[e];
    const int col = eidx[E + e];
    const int p = atomicAdd(&cur_r[row], 1);
    srt_r[p] = make_uint2((unsigned)col, (unsigned)e);
    const int q = atomicAdd(&cur_c[col], 1);
    srt_c[q] = make_uint2((unsigned)row, (unsigned)e);
}

// one wave per node: accumulate x[other] (float2 per lane) + labels, write mean once
__global__ __launch_bounds__(256) void accum_kernel(
    const float* __restrict__ x, const float* __restrict__ elabel,
    const uint2* __restrict__ srt, const int* __restrict__ rowptr,
    float* __restrict__ mean, float* __restrict__ labmean, int n)
{
    const int lane = threadIdx.x;                  // 0..63
    const int node = blockIdx.x * 4 + threadIdx.y;
    if (node >= n) return;
    const int start = rowptr[node];
    const int end   = rowptr[node + 1];
    const float2* __restrict__ x2 = (const float2*)x;
    float ax = 0.f, ay = 0.f, lab = 0.f;

    int i = start;
    for (; i + 1 < end; i += 2) {                  // 2x unroll: two gathers in flight
        const uint2 sa = srt[i];
        const uint2 sb = srt[i + 1];
        const float2 xa = x2[(size_t)sa.x * 64 + lane];
        const float2 xb = x2[(size_t)sb.x * 64 + lane];
        ax += xa.x + xb.x;
        ay += xa.y + xb.y;
        if (lane < 4)
            lab += elabel[(size_t)sa.y * 4 + lane] + elabel[(size_t)sb.y * 4 + lane];
    }
    if (i < end) {
        const uint2 sa = srt[i];
        const float2 xa = x2[(size_t)sa.x * 64 + lane];
        ax += xa.x;
        ay += xa.y;
        if (lane < 4) lab += elabel[(size_t)sa.y * 4 + lane];
    }

    const float inv = 1.0f / fmaxf((float)(end - start), 1.0f);
    ((float2*)mean)[(size_t)node * 64 + lane] = make_float2(ax * inv, ay * inv);
    if (lane < 4) labmean[(size_t)node * 4 + lane] = lab * inv;
}

// P1 = tw @ weight[128:256] (4x256), P3 = tw @ weight[384:512] (4x256)
__global__ void precompute_p(const float* __restrict__ tw, const float* __restrict__ weight,
                             float* __restrict__ P1, float* __restrict__ P3)
{
    const int o = threadIdx.x;
    #pragma unroll
    for (int l = 0; l < 4; ++l) {
        float s1 = 0.f, s3 = 0.f;
        for (int c = 0; c < 128; ++c) {
            const float t = tw[l * 128 + c];
            s1 = fmaf(t, weight[(size_t)(128 + c) * 256 + o], s1);
            s3 = fmaf(t, weight[(size_t)(384 + c) * 256 + o], s3);
        }
        P1[l * 256 + o] = s1;
        P3[l * 256 + o] = s3;
    }
}

// out[64 nodes x 256 cols] per block; K=256 main loop + rank-8 opinion epilogue
__global__ __launch_bounds__(256) void gemm_kernel(
    const float* __restrict__ out_mean, const float* __restrict__ inn_mean,
    const float* __restrict__ labr, const float* __restrict__ labc,
    const float* __restrict__ weight, const float* __restrict__ P1,
    const float* __restrict__ P3, const float* __restrict__ bias,
    float* __restrict__ out, int n_nodes)
{
    __shared__ float hs[64][33];
    __shared__ float ws[32][256];
    __shared__ float ps[8][256];
    __shared__ float labs[64][8];

    const int t = threadIdx.x;
    const int tx = t & 31;
    const int ty = t >> 5;
    const int node0 = blockIdx.x * 64;

    float acc[8][8];
    #pragma unroll
    for (int i = 0; i < 8; ++i)
        #pragma unroll
        for (int j = 0; j < 8; ++j) acc[i][j] = 0.f;

    for (int i = t; i < 2048; i += 256) {
        const int l = i >> 8, c = i & 255;
        ps[l][c] = (l < 4) ? P1[l * 256 + c] : P3[(l - 4) * 256 + c];
    }
    for (int i = t; i < 512; i += 256) {
        const int node = i >> 3, l = i & 7;
        const int gn = node0 + node;
        float v = 0.f;
        if (gn < n_nodes)
            v = (l < 4) ? labr[(size_t)gn * 4 + l] : labc[(size_t)gn * 4 + (l - 4)];
        labs[node][l] = v;
    }

    for (int kt = 0; kt < 8; ++kt) {
        const float* __restrict__ src = (kt < 4) ? out_mean : inn_mean;
        const int cbase = (kt & 3) * 32;
        const int wrow0 = (kt < 4) ? kt * 32 : 256 + (kt - 4) * 32;

        __syncthreads();

        {
            const int node = t >> 2;
            const int gn = node0 + node;
            const int kk0 = (t & 3) * 8;
            float4 a0 = make_float4(0.f, 0.f, 0.f, 0.f), a1 = a0;
            if (gn < n_nodes) {
                const float4* s4 = (const float4*)(src + (size_t)gn * 128 + cbase + kk0);
                a0 = s4[0]; a1 = s4[1];
            }
            hs[node][kk0 + 0] = a0.x;
            hs[node][kk0 + 1] = a0.y;
            hs[node][kk0 + 2] = a0.z;
            hs[node][kk0 + 3] = a0.w;
            hs[node][kk0 + 4] = a1.x;
            hs[node][kk0 + 5] = a1.y;
            hs[node][kk0 + 6] = a1.z;
            hs[node][kk0 + 7] = a1.w;
        }
        for (int kk = 0; kk < 32; ++kk)
            ws[kk][t] = weight[(size_t)(wrow0 + kk) * 256 + t];

        __syncthreads();

        for (int kk = 0; kk < 32; ++kk) {
            float a[8], b[8];
            #pragma unroll
            for (int j = 0; j < 8; ++j) b[j] = ws[kk][tx + 32 * j];
            #pragma unroll
            for (int i = 0; i < 8; ++i) a[i] = hs[ty * 8 + i][kk];
            #pragma unroll
            for (int i = 0; i < 8; ++i)
                #pragma unroll
                for (int j = 0; j < 8; ++j)
                    acc[i][j] = fmaf(a[i], b[j], acc[i][j]);
        }
    }

    #pragma unroll
    for (int i = 0; i < 8; ++i) {
        const int node = ty * 8 + i;
        const int gn = node0 + node;
        if (gn >= n_nodes) continue;
        #pragma unroll
        for (int j = 0; j < 8; ++j) {
            const int oc = tx + 32 * j;
            float v = acc[i][j] + bias[oc];
            #pragma unroll
            for (int l = 0; l < 8; ++l) v = fmaf(labs[node][l], ps[l][oc], v);
            out[(size_t)gn * 256 + oc] = v;
        }
    }
}

extern "C" void kernel_launch(void* const* d_in, const int* in_sizes, int n_in,
                              void* d_out, int out_size, void* d_ws, size_t ws_size,
                              hipStream_t stream) {
    const float* x      = (const float*)d_in[0];
    const int*   eidx   = (const int*)d_in[1];
    const float* elabel = (const float*)d_in[2];
    const float* weight = (const float*)d_in[3];
    const float* tw     = (const float*)d_in[4];
    const float* bias   = (const float*)d_in[5];

    const int n = in_sizes[0] / 128;       // n_nodes
    const int E = in_sizes[2] / 4;         // n_edges
    const int nb = (n + 1023) / 1024;

    float* wf = (float*)d_ws;
    size_t o = 0;
    float* out_mean = wf + o; o += (size_t)n * 128;
    float* inn_mean = wf + o; o += (size_t)n * 128;
    float* labr     = wf + o; o += (size_t)n * 4;
    float* labc     = wf + o; o += (size_t)n * 4;
    float* P1       = wf + o; o += 1024;
    float* P3       = wf + o; o += 1024;
    int* wi = (int*)(wf + o);
    size_t oi = 0;
    int* cnt_r  = wi + oi; oi += n;        // becomes cursor after scan3
    int* cnt_c  = wi + oi; oi += n;
    int* rptr_r = wi + oi; oi += n + 1;
    int* rptr_c = wi + oi; oi += n + 1;
    int* bsum_r = wi + oi; oi += nb;
    int* bsum_c = wi + oi; oi += nb;

    // sorted edge lists staged in d_out (consumed before gemm overwrites it)
    uint2* srt_r = (uint2*)d_out;
    uint2* srt_c = srt_r + E;

    hipMemsetAsync(cnt_r, 0, (size_t)2 * n * sizeof(int), stream);

    hipLaunchKernelGGL(precompute_p, dim3(1), dim3(256), 0, stream, tw, weight, P1, P3);

    hipLaunchKernelGGL(hist_kernel, dim3((2 * E + 255) / 256), dim3(256), 0, stream,
                       eidx, cnt_r, cnt_c, E);

    hipLaunchKernelGGL(scan1, dim3(nb), dim3(1024), 0, stream, cnt_r, bsum_r, n);
    hipLaunchKernelGGL(scan1, dim3(nb), dim3(1024), 0, stream, cnt_c, bsum_c, n);
    hipLaunchKernelGGL(scan2, dim3(1), dim3(64), 0, stream, bsum_r, nb, rptr_r, n, E);
    hipLaunchKernelGGL(scan2, dim3(1), dim3(64), 0, stream, bsum_c, nb, rptr_c, n, E);
    hipLaunchKernelGGL(scan3, dim3(nb), dim3(1024), 0, stream, cnt_r, bsum_r, rptr_r, n);
    hipLaunchKernelGGL(scan3, dim3(nb), dim3(1024), 0, stream, cnt_c, bsum_c, rptr_c, n);

    hipLaunchKernelGGL(fill_kernel, dim3((E + 255) / 256), dim3(256), 0, stream,
                       eidx, cnt_r, cnt_c, srt_r, srt_c, E);

    dim3 ablock(64, 4);
    hipLaunchKernelGGL(accum_kernel, dim3((n + 3) / 4), ablock, 0, stream,
                       x, elabel, srt_r, rptr_r, out_mean, labr, n);
    hipLaunchKernelGGL(accum_kernel, dim3((n + 3) / 4), ablock, 0, stream,
                       x, elabel, srt_c, rptr_c, inn_mean, labc, n);

    hipLaunchKernelGGL(gemm_kernel, dim3((n + 63) / 64), dim3(256), 0, stream,
                       out_mean, inn_mean, labr, labc, weight, P1, P3, bias,
                       (float*)d_out, n);
}